// Round 3
// baseline (280.591 us; speedup 1.0000x reference)
//
#include <hip/hip_runtime.h>

// GCN autoencoder: recon = (Z @ Z^T)
//   h  = X @ W1                      (10000x512 @ 512x32)
//   h1 = relu(A @ h)                 (SpMM)
//   h2 = relu(h1) @ W2
//   z  = A @ h2                      (SpMM)
//   out= z @ z^T                     (1e8 f32, 400 MB -> HBM-write-bound)
//
// R3: atomic edge-parallel SpMM (est ~150us: 15.4M fp32 L2 atomics) replaced
// by per-call CSR build (count/scan/scatter, int atomics only) + row-parallel
// gather SpMM (coalesced gathers, one store per output, no fp atomics).

constexpr int N_  = 10000;
constexpr int E_  = 320000;
constexpr int F_  = 512;
constexpr int H1_ = 32;
constexpr int H2_ = 16;

// ---------------- zero int workspace (counts + cursor) ----------------
__global__ __launch_bounds__(256) void zero_int(int* __restrict__ p, int n) {
    int i = blockIdx.x * blockDim.x + threadIdx.x;
    if (i < n) p[i] = 0;
}

// ---------------- CSR build ----------------
__global__ __launch_bounds__(256) void count_edges(const int* __restrict__ erow,
                                                   int* __restrict__ counts) {
    int e = blockIdx.x * blockDim.x + threadIdx.x;
    if (e < E_) atomicAdd(&counts[erow[e]], 1);
}

// single-block exclusive scan: 256 threads x 40 rows each (10240 >= 10001)
__global__ __launch_bounds__(256) void scan_rows(const int* __restrict__ counts,
                                                 int* __restrict__ row_ptr) {
    __shared__ int part[256];
    const int t = threadIdx.x;
    const int base = t * 40;
    int s = 0;
#pragma unroll 4
    for (int i = 0; i < 40; ++i) {
        int r = base + i;
        if (r < N_) s += counts[r];
    }
    part[t] = s;
    __syncthreads();
    // Hillis-Steele inclusive scan
    for (int off = 1; off < 256; off <<= 1) {
        int v = (t >= off) ? part[t - off] : 0;
        __syncthreads();
        part[t] += v;
        __syncthreads();
    }
    int run = (t == 0) ? 0 : part[t - 1];   // exclusive prefix
    for (int i = 0; i < 40; ++i) {
        int r = base + i;
        if (r < N_) { row_ptr[r] = run; run += counts[r]; }
    }
    if (t == 255) row_ptr[N_] = run;        // == E_
}

__global__ __launch_bounds__(256) void scatter_edges(const int* __restrict__ erow,
                                                     const int* __restrict__ ecol,
                                                     const float* __restrict__ ew,
                                                     const int* __restrict__ row_ptr,
                                                     int* __restrict__ cursor,
                                                     int* __restrict__ col2,
                                                     float* __restrict__ w2) {
    int e = blockIdx.x * blockDim.x + threadIdx.x;
    if (e >= E_) return;
    int r = erow[e];
    int p = row_ptr[r] + atomicAdd(&cursor[r], 1);
    col2[p] = ecol[e];
    w2[p]   = ew[e];
}

// ---------------- row-parallel gather SpMM ----------------
// thread (r, f): out[r][f] = sum_p w2[p] * h[col2[p]][f]  over row r's edges.
// HF consecutive threads share a row: edge scalars broadcast, h-row gather is
// a contiguous HF*4B segment. One store per output, no fp atomics.
template <int HF, bool RELU>
__global__ __launch_bounds__(256) void spmm_csr(const float* __restrict__ h,
                                                const int* __restrict__ row_ptr,
                                                const int* __restrict__ col2,
                                                const float* __restrict__ w2,
                                                float* __restrict__ out) {
    int tid = blockIdx.x * blockDim.x + threadIdx.x;
    if (tid >= N_ * HF) return;
    int r = tid / HF;
    int f = tid & (HF - 1);
    int beg = row_ptr[r];
    int end = row_ptr[r + 1];
    float acc = 0.f;
    for (int p = beg; p < end; ++p) {
        int c   = col2[p];
        float w = w2[p];
        acc = fmaf(w, h[(size_t)c * HF + f], acc);
    }
    out[(size_t)r * HF + f] = RELU ? fmaxf(acc, 0.f) : acc;
}

// ---------------- h = X @ W1 ----------------
__global__ __launch_bounds__(256) void gemm_xw1(const float* __restrict__ x,
                                                const float* __restrict__ W1,
                                                float* __restrict__ h) {
    int tid = blockIdx.x * blockDim.x + threadIdx.x;
    if (tid >= N_ * H1_) return;
    int r = tid >> 5;          // /32
    int c = tid & (H1_ - 1);
    const float4* xr = reinterpret_cast<const float4*>(x + (size_t)r * F_);
    float acc = 0.f;
#pragma unroll 8
    for (int k4 = 0; k4 < F_ / 4; ++k4) {
        float4 xv = xr[k4];
        int k = k4 * 4;
        acc = fmaf(xv.x, W1[(k + 0) * H1_ + c], acc);
        acc = fmaf(xv.y, W1[(k + 1) * H1_ + c], acc);
        acc = fmaf(xv.z, W1[(k + 2) * H1_ + c], acc);
        acc = fmaf(xv.w, W1[(k + 3) * H1_ + c], acc);
    }
    h[tid] = acc;
}

// ---------------- h2 = relu(h1) @ W2 ----------------
__global__ __launch_bounds__(256) void gemm_h1w2(const float* __restrict__ h1,
                                                 const float* __restrict__ W2,
                                                 float* __restrict__ h2) {
    int tid = blockIdx.x * blockDim.x + threadIdx.x;
    if (tid >= N_ * H2_) return;
    int r = tid >> 4;          // /16
    int c = tid & (H2_ - 1);
    const float* hr = h1 + (size_t)r * H1_;
    float acc = 0.f;
#pragma unroll
    for (int k = 0; k < H1_; ++k)
        acc = fmaf(fmaxf(hr[k], 0.f), W2[k * H2_ + c], acc);
    h2[tid] = acc;
}

// ---------------- out = z @ z^T ----------------
constexpr int BI = 32;
constexpr int BJ = 128;

__global__ __launch_bounds__(256) void zzt(const float* __restrict__ z,
                                           float* __restrict__ out) {
    __shared__ float zi[H2_][BI + 4];
    __shared__ float zj[H2_][BJ + 4];
    const int t  = threadIdx.x;
    const int ib = blockIdx.y * BI;
    const int jb = blockIdx.x * BJ;

    for (int idx = t; idx < BI * H2_; idx += 256) {
        int rl = idx >> 4;
        int k  = idx & 15;
        int gr = ib + rl;
        zi[k][rl] = (gr < N_) ? z[(size_t)gr * H2_ + k] : 0.f;
    }
    for (int idx = t; idx < BJ * H2_; idx += 256) {
        int rl = idx >> 4;
        int k  = idx & 15;
        int gr = jb + rl;
        zj[k][rl] = (gr < N_) ? z[(size_t)gr * H2_ + k] : 0.f;
    }
    __syncthreads();

    const int il = (t >> 5) << 2;   // 0,4,...,28
    const int jl = (t & 31) << 2;   // 0,4,...,124

    float acc[4][4] = {};
#pragma unroll
    for (int k = 0; k < H2_; ++k) {
        float4 a = *reinterpret_cast<const float4*>(&zi[k][il]);
        float4 b = *reinterpret_cast<const float4*>(&zj[k][jl]);
        acc[0][0] = fmaf(a.x, b.x, acc[0][0]);
        acc[0][1] = fmaf(a.x, b.y, acc[0][1]);
        acc[0][2] = fmaf(a.x, b.z, acc[0][2]);
        acc[0][3] = fmaf(a.x, b.w, acc[0][3]);
        acc[1][0] = fmaf(a.y, b.x, acc[1][0]);
        acc[1][1] = fmaf(a.y, b.y, acc[1][1]);
        acc[1][2] = fmaf(a.y, b.z, acc[1][2]);
        acc[1][3] = fmaf(a.y, b.w, acc[1][3]);
        acc[2][0] = fmaf(a.z, b.x, acc[2][0]);
        acc[2][1] = fmaf(a.z, b.y, acc[2][1]);
        acc[2][2] = fmaf(a.z, b.z, acc[2][2]);
        acc[2][3] = fmaf(a.z, b.w, acc[2][3]);
        acc[3][0] = fmaf(a.w, b.x, acc[3][0]);
        acc[3][1] = fmaf(a.w, b.y, acc[3][1]);
        acc[3][2] = fmaf(a.w, b.z, acc[3][2]);
        acc[3][3] = fmaf(a.w, b.w, acc[3][3]);
    }

#pragma unroll
    for (int ii = 0; ii < 4; ++ii) {
        int gi = ib + il + ii;
        if (gi >= N_) continue;
        int gj = jb + jl;
        float* orow = out + (size_t)gi * N_ + gj;
        if (gj + 3 < N_) {
            *reinterpret_cast<float4*>(orow) =
                make_float4(acc[ii][0], acc[ii][1], acc[ii][2], acc[ii][3]);
        } else {
#pragma unroll
            for (int jj = 0; jj < 4; ++jj)
                if (gj + jj < N_) orow[jj] = acc[ii][jj];
        }
    }
}

extern "C" void kernel_launch(void* const* d_in, const int* in_sizes, int n_in,
                              void* d_out, int out_size, void* d_ws, size_t ws_size,
                              hipStream_t stream) {
    const float* x    = (const float*)d_in[0];
    const float* ew   = (const float*)d_in[1];
    const float* W1   = (const float*)d_in[2];
    const float* W2   = (const float*)d_in[3];
    const int*   erow = (const int*)d_in[4];
    const int*   ecol = (const int*)d_in[5];
    float* out = (float*)d_out;

    // workspace layout (all 4B elements)
    float* h       = (float*)d_ws;             // N*H1
    float* h1      = h  + N_ * H1_;            // N*H1
    float* h2      = h1 + N_ * H1_;            // N*H2
    float* z       = h2 + N_ * H2_;            // N*H2
    float* w2      = z  + N_ * H2_;            // E
    int*   col2    = (int*)(w2 + E_);          // E
    int*   counts  = col2 + E_;                // N
    int*   cursor  = counts + N_;              // N
    int*   row_ptr = cursor + N_;              // N+1

    // --- CSR build (reused by both SpMM layers) ---
    zero_int<<<(2 * N_ + 255) / 256, 256, 0, stream>>>(counts, 2 * N_); // counts+cursor
    count_edges<<<(E_ + 255) / 256, 256, 0, stream>>>(erow, counts);
    scan_rows<<<1, 256, 0, stream>>>(counts, row_ptr);
    scatter_edges<<<(E_ + 255) / 256, 256, 0, stream>>>(erow, ecol, ew, row_ptr,
                                                        cursor, col2, w2);

    // --- dense pipeline ---
    gemm_xw1<<<(N_ * H1_ + 255) / 256, 256, 0, stream>>>(x, W1, h);
    spmm_csr<H1_, true><<<(N_ * H1_ + 255) / 256, 256, 0, stream>>>(h, row_ptr, col2, w2, h1);
    gemm_h1w2<<<(N_ * H2_ + 255) / 256, 256, 0, stream>>>(h1, W2, h2);
    spmm_csr<H2_, false><<<(N_ * H2_ + 255) / 256, 256, 0, stream>>>(h2, row_ptr, col2, w2, z);

    dim3 grid((N_ + BJ - 1) / BJ, (N_ + BI - 1) / BI);
    zzt<<<grid, 256, 0, stream>>>(z, out);
}

// Round 4
// 216.104 us; speedup vs baseline: 1.2984x; 1.2984x over previous
//
#include <hip/hip_runtime.h>

// GCN autoencoder: recon = (Z @ Z^T)
//   h  = X @ W1   (10000x512 @ 512x32)
//   h1 = relu(A @ h);  h2 = h1 @ W2   (fused, h1 stays in LDS)
//   z  = A @ h2
//   out= z @ z^T  (1e8 f32, 400 MB -> HBM-write-bound, ~57 us floor)
//
// R4: bisect the R3 regression. CSR count/scan/scatter chain (3 kernels)
// replaced by ONE scatter into a fixed-capacity ELL table (cap 96 >> max
// Poisson(32) degree). Gather SpMM keeps "no fp atomics, one store per
// output, no pre-zero". 5 kernels total: [xw1 || zero-cursor] -> scatter ->
// spmm1+mlp -> spmm2 -> zzt. Gather loop hand-unrolled x4 for 4 loads in
// flight (breaks col->h dependent latency chain).

constexpr int N_   = 10000;
constexpr int E_   = 320000;
constexpr int F_   = 512;
constexpr int H1_  = 32;
constexpr int H2_  = 16;
constexpr int CAP_ = 96;   // ELL row capacity; P[Poisson(32) > 96] ~ 3e-20

// ---------------- K1: h = X @ W1, side blocks zero cursor ----------------
constexpr int GEMM_BLOCKS = (N_ * H1_) / 256;           // 1250
constexpr int ZERO_BLOCKS = (N_ + 255) / 256;           // 40

__global__ __launch_bounds__(256) void gemm_xw1_zero(const float* __restrict__ x,
                                                     const float* __restrict__ W1,
                                                     float* __restrict__ h,
                                                     int* __restrict__ cursor) {
    if (blockIdx.x >= GEMM_BLOCKS) {
        int i = (blockIdx.x - GEMM_BLOCKS) * 256 + threadIdx.x;
        if (i < N_) cursor[i] = 0;
        return;
    }
    int tid = blockIdx.x * blockDim.x + threadIdx.x;
    int r = tid >> 5;          // /32
    int c = tid & (H1_ - 1);
    const float4* xr = reinterpret_cast<const float4*>(x + (size_t)r * F_);
    float acc = 0.f;
#pragma unroll 8
    for (int k4 = 0; k4 < F_ / 4; ++k4) {
        float4 xv = xr[k4];
        int k = k4 * 4;
        acc = fmaf(xv.x, W1[(k + 0) * H1_ + c], acc);
        acc = fmaf(xv.y, W1[(k + 1) * H1_ + c], acc);
        acc = fmaf(xv.z, W1[(k + 2) * H1_ + c], acc);
        acc = fmaf(xv.w, W1[(k + 3) * H1_ + c], acc);
    }
    h[tid] = acc;
}

// ---------------- K2: scatter edges into ELL rows ----------------
__global__ __launch_bounds__(256) void scatter_ell(const int* __restrict__ erow,
                                                   const int* __restrict__ ecol,
                                                   const float* __restrict__ ew,
                                                   int* __restrict__ cursor,
                                                   int* __restrict__ cole,
                                                   float* __restrict__ we) {
    int e = blockIdx.x * blockDim.x + threadIdx.x;
    if (e >= E_) return;
    int r = erow[e];
    int p = atomicAdd(&cursor[r], 1);
    if (p < CAP_) {                       // overflow-impossible guard
        size_t idx = (size_t)r * CAP_ + p;
        cole[idx] = ecol[e];
        we[idx]   = ew[e];
    }
}

// ---------------- K3: h2 = relu(A @ h) @ W2  (8 rows / block) ----------------
__global__ __launch_bounds__(256) void spmm1_mlp(const float* __restrict__ h,
                                                 const int* __restrict__ cursor,
                                                 const int* __restrict__ cole,
                                                 const float* __restrict__ we,
                                                 const float* __restrict__ W2,
                                                 float* __restrict__ h2) {
    __shared__ float sh1[8][H1_ + 1];
    __shared__ float sW2[H1_ * H2_];
    const int t = threadIdx.x;
    sW2[t]       = W2[t];
    sW2[t + 256] = W2[t + 256];

    const int rl = t >> 5;           // 0..7
    const int f  = t & (H1_ - 1);
    const int r  = blockIdx.x * 8 + rl;
    float acc = 0.f;
    if (r < N_) {
        const int deg = cursor[r];
        const int*   cp = cole + (size_t)r * CAP_;
        const float* wp = we   + (size_t)r * CAP_;
        int p = 0;
        for (; p + 4 <= deg; p += 4) {
            int c0 = cp[p], c1 = cp[p + 1], c2 = cp[p + 2], c3 = cp[p + 3];
            float w0 = wp[p], w1 = wp[p + 1], w2v = wp[p + 2], w3 = wp[p + 3];
            float g0 = h[(size_t)c0 * H1_ + f];
            float g1 = h[(size_t)c1 * H1_ + f];
            float g2 = h[(size_t)c2 * H1_ + f];
            float g3 = h[(size_t)c3 * H1_ + f];
            acc = fmaf(w0, g0, acc);
            acc = fmaf(w1, g1, acc);
            acc = fmaf(w2v, g2, acc);
            acc = fmaf(w3, g3, acc);
        }
        for (; p < deg; ++p)
            acc = fmaf(wp[p], h[(size_t)cp[p] * H1_ + f], acc);
    }
    sh1[rl][f] = fmaxf(acc, 0.f);     // relu fused here
    __syncthreads();

    if (t < 128) {
        const int r2l = t >> 4;       // 0..7
        const int c   = t & (H2_ - 1);
        const int r2  = blockIdx.x * 8 + r2l;
        if (r2 < N_) {
            float a = 0.f;
#pragma unroll
            for (int k = 0; k < H1_; ++k)
                a = fmaf(sh1[r2l][k], sW2[k * H2_ + c], a);
            h2[(size_t)r2 * H2_ + c] = a;
        }
    }
}

// ---------------- K4: z = A @ h2  (16 rows / block) ----------------
__global__ __launch_bounds__(256) void spmm2(const float* __restrict__ h2,
                                             const int* __restrict__ cursor,
                                             const int* __restrict__ cole,
                                             const float* __restrict__ we,
                                             float* __restrict__ z) {
    const int t = threadIdx.x;
    const int rl = t >> 4;            // 0..15
    const int f  = t & (H2_ - 1);
    const int r  = blockIdx.x * 16 + rl;
    if (r >= N_) return;
    const int deg = cursor[r];
    const int*   cp = cole + (size_t)r * CAP_;
    const float* wp = we   + (size_t)r * CAP_;
    float acc = 0.f;
    int p = 0;
    for (; p + 4 <= deg; p += 4) {
        int c0 = cp[p], c1 = cp[p + 1], c2 = cp[p + 2], c3 = cp[p + 3];
        float w0 = wp[p], w1 = wp[p + 1], w2v = wp[p + 2], w3 = wp[p + 3];
        float g0 = h2[(size_t)c0 * H2_ + f];
        float g1 = h2[(size_t)c1 * H2_ + f];
        float g2 = h2[(size_t)c2 * H2_ + f];
        float g3 = h2[(size_t)c3 * H2_ + f];
        acc = fmaf(w0, g0, acc);
        acc = fmaf(w1, g1, acc);
        acc = fmaf(w2v, g2, acc);
        acc = fmaf(w3, g3, acc);
    }
    for (; p < deg; ++p)
        acc = fmaf(wp[p], h2[(size_t)cp[p] * H2_ + f], acc);
    z[(size_t)r * H2_ + f] = acc;
}

// ---------------- K5: out = z @ z^T ----------------
constexpr int BI = 32;
constexpr int BJ = 128;

__global__ __launch_bounds__(256) void zzt(const float* __restrict__ z,
                                           float* __restrict__ out) {
    __shared__ float zi[H2_][BI + 4];
    __shared__ float zj[H2_][BJ + 4];
    const int t  = threadIdx.x;
    const int ib = blockIdx.y * BI;
    const int jb = blockIdx.x * BJ;

    for (int idx = t; idx < BI * H2_; idx += 256) {
        int rl = idx >> 4;
        int k  = idx & 15;
        int gr = ib + rl;
        zi[k][rl] = (gr < N_) ? z[(size_t)gr * H2_ + k] : 0.f;
    }
    for (int idx = t; idx < BJ * H2_; idx += 256) {
        int rl = idx >> 4;
        int k  = idx & 15;
        int gr = jb + rl;
        zj[k][rl] = (gr < N_) ? z[(size_t)gr * H2_ + k] : 0.f;
    }
    __syncthreads();

    const int il = (t >> 5) << 2;   // 0,4,...,28
    const int jl = (t & 31) << 2;   // 0,4,...,124

    float acc[4][4] = {};
#pragma unroll
    for (int k = 0; k < H2_; ++k) {
        float4 a = *reinterpret_cast<const float4*>(&zi[k][il]);
        float4 b = *reinterpret_cast<const float4*>(&zj[k][jl]);
        acc[0][0] = fmaf(a.x, b.x, acc[0][0]);
        acc[0][1] = fmaf(a.x, b.y, acc[0][1]);
        acc[0][2] = fmaf(a.x, b.z, acc[0][2]);
        acc[0][3] = fmaf(a.x, b.w, acc[0][3]);
        acc[1][0] = fmaf(a.y, b.x, acc[1][0]);
        acc[1][1] = fmaf(a.y, b.y, acc[1][1]);
        acc[1][2] = fmaf(a.y, b.z, acc[1][2]);
        acc[1][3] = fmaf(a.y, b.w, acc[1][3]);
        acc[2][0] = fmaf(a.z, b.x, acc[2][0]);
        acc[2][1] = fmaf(a.z, b.y, acc[2][1]);
        acc[2][2] = fmaf(a.z, b.z, acc[2][2]);
        acc[2][3] = fmaf(a.z, b.w, acc[2][3]);
        acc[3][0] = fmaf(a.w, b.x, acc[3][0]);
        acc[3][1] = fmaf(a.w, b.y, acc[3][1]);
        acc[3][2] = fmaf(a.w, b.z, acc[3][2]);
        acc[3][3] = fmaf(a.w, b.w, acc[3][3]);
    }

#pragma unroll
    for (int ii = 0; ii < 4; ++ii) {
        int gi = ib + il + ii;
        if (gi >= N_) continue;
        int gj = jb + jl;
        float* orow = out + (size_t)gi * N_ + gj;
        if (gj + 3 < N_) {
            *reinterpret_cast<float4*>(orow) =
                make_float4(acc[ii][0], acc[ii][1], acc[ii][2], acc[ii][3]);
        } else {
#pragma unroll
            for (int jj = 0; jj < 4; ++jj)
                if (gj + jj < N_) orow[jj] = acc[ii][jj];
        }
    }
}

extern "C" void kernel_launch(void* const* d_in, const int* in_sizes, int n_in,
                              void* d_out, int out_size, void* d_ws, size_t ws_size,
                              hipStream_t stream) {
    const float* x    = (const float*)d_in[0];
    const float* ew   = (const float*)d_in[1];
    const float* W1   = (const float*)d_in[2];
    const float* W2   = (const float*)d_in[3];
    const int*   erow = (const int*)d_in[4];
    const int*   ecol = (const int*)d_in[5];
    float* out = (float*)d_out;

    // workspace layout (4B elements)
    float* h      = (float*)d_ws;              // N*H1
    float* h2     = h  + (size_t)N_ * H1_;     // N*H2
    float* z      = h2 + (size_t)N_ * H2_;     // N*H2
    float* we     = z  + (size_t)N_ * H2_;     // N*CAP
    int*   cole   = (int*)(we + (size_t)N_ * CAP_);   // N*CAP
    int*   cursor = cole + (size_t)N_ * CAP_;  // N

    gemm_xw1_zero<<<GEMM_BLOCKS + ZERO_BLOCKS, 256, 0, stream>>>(x, W1, h, cursor);
    scatter_ell<<<(E_ + 255) / 256, 256, 0, stream>>>(erow, ecol, ew, cursor, cole, we);
    spmm1_mlp<<<(N_ + 7) / 8, 256, 0, stream>>>(h, cursor, cole, we, W2, h2);
    spmm2<<<(N_ + 15) / 16, 256, 0, stream>>>(h2, cursor, cole, we, z);

    dim3 grid((N_ + BJ - 1) / BJ, (N_ + BI - 1) / BI);
    zzt<<<grid, 256, 0, stream>>>(z, out);
}